// Round 1
// baseline (200.451 us; speedup 1.0000x reference)
//
#include <hip/hip_runtime.h>

#define S_LEN 4096
#define EMBD  1024
#define HEADD 64
#define QT    32

typedef __bf16 bf16x8 __attribute__((ext_vector_type(8)));
typedef float  f32x4  __attribute__((ext_vector_type(4)));

__device__ __forceinline__ unsigned short f2bf(float f) {
  union { float f; unsigned u; } x; x.f = f;
  unsigned r = x.u + 0x7FFFu + ((x.u >> 16) & 1u);
  return (unsigned short)(r >> 16);
}

__device__ __forceinline__ bf16x8 cvt8(f32x4 a, f32x4 b) {
  union { bf16x8 v; unsigned short s[8]; } u;
#pragma unroll
  for (int j = 0; j < 4; j++) { u.s[j] = f2bf(a[j]); u.s[4 + j] = f2bf(b[j]); }
  return u.v;
}

// ---------------- Kernel 0: W transpose/convert + bias, fold softmax scale into Q ----
__global__ void prep_w(const float* __restrict__ Wk, const float* __restrict__ bk,
                       const float* __restrict__ Wq, const float* __restrict__ bq,
                       const float* __restrict__ Wv, const float* __restrict__ bv,
                       unsigned short* __restrict__ wt, float* __restrict__ bias) {
  int n = blockIdx.x;            // 0..191 : [0,64)=K, [64,128)=Q(scaled), [128,192)=V
  int t = threadIdx.x;
  const float QSCALE = 0.125f * 1.44269504088896340736f;  // 1/sqrt(64) * log2(e)
  const float* W; const float* b; int col; float s;
  if (n < 64)       { W = Wk; b = bk; col = n;       s = 1.0f;   }
  else if (n < 128) { W = Wq; b = bq; col = n - 64;  s = QSCALE; }
  else              { W = Wv; b = bv; col = n - 128; s = QSCALE * 0.0f + ((void)0, 1.0f); }
  if (n >= 128) s = 1.0f;
  for (int k = t; k < EMBD; k += 256)
    wt[n * EMBD + k] = f2bf(W[k * HEADD + col] * s);
  if (t == 0) bias[n] = b[col] * s;
}

// ---------------- Kernel 1: fused QKV projection (MFMA bf16) ------------------------
// grid 256 x 256 threads; block = 64 rows; wave = 16 rows; N=192 (K|Q|V)
__global__ __launch_bounds__(256) void proj_qkv(
    const float* __restrict__ X, const unsigned short* __restrict__ wt,
    const float* __restrict__ bias,
    unsigned short* __restrict__ qws, unsigned short* __restrict__ kws,
    unsigned short* __restrict__ vtws) {
  const int wave = threadIdx.x >> 6;
  const int lane = threadIdx.x & 63;
  const int l15 = lane & 15, lg = lane >> 4;
  const int arow = blockIdx.x * 64 + wave * 16 + l15;
  const float* xrow = X + (size_t)arow * EMBD + lg * 8;
  const unsigned short* wp = wt + (size_t)l15 * EMBD + lg * 8;

  f32x4 acc[12];
#pragma unroll
  for (int i = 0; i < 12; i++) acc[i] = (f32x4){0.f, 0.f, 0.f, 0.f};

  for (int kc = 0; kc < EMBD; kc += 32) {
    f32x4 xa = *(const f32x4*)(xrow + kc);
    f32x4 xb = *(const f32x4*)(xrow + kc + 4);
    bf16x8 afrag = cvt8(xa, xb);
#pragma unroll
    for (int nf = 0; nf < 12; nf++) {
      bf16x8 bfrag = *(const bf16x8*)(wp + (size_t)nf * 16 * EMBD + kc);
      acc[nf] = __builtin_amdgcn_mfma_f32_16x16x32_bf16(afrag, bfrag, acc[nf], 0, 0, 0);
    }
  }

  const int crow0 = blockIdx.x * 64 + wave * 16 + lg * 4;
#pragma unroll
  for (int nf = 0; nf < 12; nf++) {
    int n = nf * 16 + l15;
    float bs = bias[n];
#pragma unroll
    for (int i = 0; i < 4; i++) {
      int r = crow0 + i;
      unsigned short h = f2bf(acc[nf][i] + bs);
      if (nf < 4) {
        kws[(size_t)r * HEADD + n] = h;
      } else if (nf < 8) {
        qws[(size_t)r * HEADD + (n - 64)] = h;
      } else {
        int d = n - 128;
        int b = r >> 12, srow = r & 4095;
        vtws[((size_t)b * HEADD + d) * S_LEN + srow] = h;  // V stored transposed
      }
    }
  }
}

// ---------------- Kernel 2: causal flash attention --------------------------------
// grid 512 x 128 threads (2 waves); block = 32 q-rows; wave = 16 q-rows; kv-tile 64
__global__ __launch_bounds__(128) void attn(
    const unsigned short* __restrict__ qws,
    const unsigned short* __restrict__ kws,
    const unsigned short* __restrict__ vtws,
    float* __restrict__ out) {
  __shared__ unsigned short pl[2][16][72];  // per-wave P bounce, +8 pad (2-way bank only)

  const int wave = threadIdx.x >> 6;
  const int lane = threadIdx.x & 63;
  const int l15 = lane & 15, lg = lane >> 4;

  int idx = blockIdx.x;
  int half = idx >> 8;          // pair heavy (first 256) with light (last 256)
  int j = (idx & 255) >> 2;
  int qt = half ? j : 127 - j;
  int b = idx & 3;
  const int qbase = qt * QT;

  const unsigned short* qp =
      qws + ((size_t)b * S_LEN + qbase + wave * 16 + l15) * HEADD + lg * 8;
  bf16x8 aq0 = *(const bf16x8*)qp;
  bf16x8 aq1 = *(const bf16x8*)(qp + 32);

  const unsigned short* kb = kws + (size_t)b * S_LEN * HEADD;
  const unsigned short* vb = vtws + (size_t)b * HEADD * S_LEN;

  f32x4 o[4];
  float m[4], l[4];
#pragma unroll
  for (int i = 0; i < 4; i++) { o[i] = (f32x4){0.f,0.f,0.f,0.f}; m[i] = -3.0e38f; l[i] = 0.f; }

  const int tful = qbase >> 6;
  const int tlast = (qbase + QT - 1) >> 6;

  for (int t = 0; t <= tlast; t++) {
    // ---- S = Q K^T (scale+log2e pre-folded into Q) ----
    f32x4 sc[4];
    const unsigned short* kt = kb + ((size_t)t * 64 + l15) * HEADD + lg * 8;
#pragma unroll
    for (int nf = 0; nf < 4; nf++) {
      bf16x8 b0 = *(const bf16x8*)(kt + (size_t)nf * 16 * HEADD);
      bf16x8 b1 = *(const bf16x8*)(kt + (size_t)nf * 16 * HEADD + 32);
      f32x4 z = (f32x4){0.f,0.f,0.f,0.f};
      z = __builtin_amdgcn_mfma_f32_16x16x32_bf16(aq0, b0, z, 0, 0, 0);
      sc[nf] = __builtin_amdgcn_mfma_f32_16x16x32_bf16(aq1, b1, z, 0, 0, 0);
    }
    // ---- causal mask (diagonal tile only) ----
    if (t >= tful) {
#pragma unroll
      for (int nf = 0; nf < 4; nf++)
#pragma unroll
        for (int i = 0; i < 4; i++) {
          int kv = t * 64 + nf * 16 + l15;
          int qr = qbase + wave * 16 + lg * 4 + i;
          if (kv > qr) sc[nf][i] = -1.0e30f;
        }
    }
    // ---- online softmax: row max over 16-lane group ----
    float mx[4];
#pragma unroll
    for (int i = 0; i < 4; i++)
      mx[i] = fmaxf(fmaxf(sc[0][i], sc[1][i]), fmaxf(sc[2][i], sc[3][i]));
#pragma unroll
    for (int i = 0; i < 4; i++) {
      mx[i] = fmaxf(mx[i], __shfl_xor(mx[i], 1));
      mx[i] = fmaxf(mx[i], __shfl_xor(mx[i], 2));
      mx[i] = fmaxf(mx[i], __shfl_xor(mx[i], 4));
      mx[i] = fmaxf(mx[i], __shfl_xor(mx[i], 8));
    }
    float al[4];
#pragma unroll
    for (int i = 0; i < 4; i++) {
      float mn = fmaxf(m[i], mx[i]);
      al[i] = exp2f(m[i] - mn);
      m[i] = mn;
    }
    // ---- P = exp2(s - m); row sums; P -> LDS (bf16) ----
    float rs[4] = {0.f, 0.f, 0.f, 0.f};
#pragma unroll
    for (int nf = 0; nf < 4; nf++) {
#pragma unroll
      for (int i = 0; i < 4; i++) {
        float p = exp2f(sc[nf][i] - m[i]);
        rs[i] += p;
        pl[wave][lg * 4 + i][nf * 16 + l15] = f2bf(p);
      }
    }
#pragma unroll
    for (int i = 0; i < 4; i++) {
      rs[i] += __shfl_xor(rs[i], 1);
      rs[i] += __shfl_xor(rs[i], 2);
      rs[i] += __shfl_xor(rs[i], 4);
      rs[i] += __shfl_xor(rs[i], 8);
      l[i] = l[i] * al[i] + rs[i];
    }
    __syncthreads();   // P writes -> A-frag reads (wave-private, but order via barrier)
    bf16x8 ap0 = *(const bf16x8*)&pl[wave][l15][lg * 8];
    bf16x8 ap1 = *(const bf16x8*)&pl[wave][l15][32 + lg * 8];
    // ---- O = diag(alpha) O + P V ----
    const unsigned short* vt = vb + (size_t)l15 * S_LEN + t * 64 + lg * 8;
#pragma unroll
    for (int nd = 0; nd < 4; nd++) {
      bf16x8 v0 = *(const bf16x8*)(vt + (size_t)nd * 16 * S_LEN);
      bf16x8 v1 = *(const bf16x8*)(vt + (size_t)nd * 16 * S_LEN + 32);
      f32x4 oo = o[nd];
#pragma unroll
      for (int i = 0; i < 4; i++) oo[i] *= al[i];
      oo = __builtin_amdgcn_mfma_f32_16x16x32_bf16(ap0, v0, oo, 0, 0, 0);
      o[nd] = __builtin_amdgcn_mfma_f32_16x16x32_bf16(ap1, v1, oo, 0, 0, 0);
    }
    __syncthreads();   // protect pl before next iteration's writes
  }

  // ---- epilogue: O / l ----
  const int orow = qbase + wave * 16 + lg * 4;
  float inv[4];
#pragma unroll
  for (int i = 0; i < 4; i++) inv[i] = 1.0f / l[i];
#pragma unroll
  for (int nd = 0; nd < 4; nd++)
#pragma unroll
    for (int i = 0; i < 4; i++)
      out[((size_t)b * S_LEN + orow + i) * HEADD + nd * 16 + l15] = o[nd][i] * inv[i];
}

extern "C" void kernel_launch(void* const* d_in, const int* in_sizes, int n_in,
                              void* d_out, int out_size, void* d_ws, size_t ws_size,
                              hipStream_t stream) {
  const float* X  = (const float*)d_in[0];
  const float* Wk = (const float*)d_in[1];
  const float* bk = (const float*)d_in[2];
  const float* Wq = (const float*)d_in[3];
  const float* bq = (const float*)d_in[4];
  const float* Wv = (const float*)d_in[5];
  const float* bv = (const float*)d_in[6];
  float* out = (float*)d_out;

  char* ws = (char*)d_ws;
  unsigned short* kws  = (unsigned short*)(ws);                      // 2 MB
  unsigned short* qws  = (unsigned short*)(ws + (2u << 20));         // 2 MB
  unsigned short* vtws = (unsigned short*)(ws + (4u << 20));         // 2 MB (transposed)
  unsigned short* wt   = (unsigned short*)(ws + (6u << 20));         // 384 KB
  float*          bias = (float*)(ws + (6u << 20) + (512u << 10));   // 768 B

  prep_w<<<dim3(192), dim3(256), 0, stream>>>(Wk, bk, Wq, bq, Wv, bv, wt, bias);
  proj_qkv<<<dim3(256), dim3(256), 0, stream>>>(X, wt, bias, qws, kws, vtws);
  attn<<<dim3(512), dim3(128), 0, stream>>>(qws, kws, vtws, out);
}

// Round 2
// 172.045 us; speedup vs baseline: 1.1651x; 1.1651x over previous
//
#include <hip/hip_runtime.h>

#define S_LEN 4096
#define EMBD  1024
#define HEADD 64

typedef __bf16 bf16x8 __attribute__((ext_vector_type(8)));
typedef __bf16 bf16x4 __attribute__((ext_vector_type(4)));
typedef float  f32x4  __attribute__((ext_vector_type(4)));

__device__ __forceinline__ unsigned short f2bf(float f) {
  union { float f; unsigned u; } x; x.f = f;
  unsigned r = x.u + 0x7FFFu + ((x.u >> 16) & 1u);
  return (unsigned short)(r >> 16);
}

__device__ __forceinline__ bf16x8 cvt8(f32x4 a, f32x4 b) {
  union { bf16x8 v; unsigned short s[8]; } u;
#pragma unroll
  for (int j = 0; j < 4; j++) { u.s[j] = f2bf(a[j]); u.s[4 + j] = f2bf(b[j]); }
  return u.v;
}

// ---------------- Kernel 0: W transpose/convert + bias; fold scale*log2e into Q ----
__global__ void prep_w(const float* __restrict__ Wk, const float* __restrict__ bk,
                       const float* __restrict__ Wq, const float* __restrict__ bq,
                       const float* __restrict__ Wv, const float* __restrict__ bv,
                       unsigned short* __restrict__ wt, float* __restrict__ bias) {
  int n = blockIdx.x;            // 0..191 : [0,64)=K, [64,128)=Q(scaled), [128,192)=V
  int t = threadIdx.x;
  const float QSCALE = 0.125f * 1.44269504088896340736f;  // 1/sqrt(64) * log2(e)
  const float* W; const float* bsrc; int col; float s = 1.0f;
  if (n < 64)       { W = Wk; bsrc = bk; col = n; }
  else if (n < 128) { W = Wq; bsrc = bq; col = n - 64; s = QSCALE; }
  else              { W = Wv; bsrc = bv; col = n - 128; }
  for (int k = t; k < EMBD; k += 256)
    wt[n * EMBD + k] = f2bf(W[k * HEADD + col] * s);
  if (t == 0) bias[n] = bsrc[col] * s;
}

// ---------------- Kernel 1: QKV projection, col-split 3 (K|Q|V per block) -----------
// grid 768 (= 256 row-groups x 3 outputs) x 256 threads; wave = 16 rows x 64 cols
__global__ __launch_bounds__(256) void proj_qkv(
    const float* __restrict__ X, const unsigned short* __restrict__ wt,
    const float* __restrict__ bias,
    unsigned short* __restrict__ qws, unsigned short* __restrict__ kws,
    unsigned short* __restrict__ vtws) {
  const int wave = threadIdx.x >> 6;
  const int lane = threadIdx.x & 63;
  const int l15 = lane & 15, lg = lane >> 4;
  const int cs = blockIdx.x % 3;          // adjacent cs share X rows -> L2/L3 hit
  const int rg = blockIdx.x / 3;
  const int arow = rg * 64 + wave * 16 + l15;
  const float* xrow = X + (size_t)arow * EMBD + lg * 8;
  const unsigned short* wp = wt + (size_t)(cs * 64 + l15) * EMBD + lg * 8;

  f32x4 acc[4];
#pragma unroll
  for (int i = 0; i < 4; i++) acc[i] = (f32x4){0.f, 0.f, 0.f, 0.f};

  f32x4 xa = *(const f32x4*)(xrow);
  f32x4 xb = *(const f32x4*)(xrow + 4);
  for (int kc = 0; kc < EMBD; kc += 32) {
    f32x4 na, nb;
    const bool hn = (kc + 32) < EMBD;
    if (hn) {
      na = *(const f32x4*)(xrow + kc + 32);
      nb = *(const f32x4*)(xrow + kc + 36);
    }
    bf16x8 afrag = cvt8(xa, xb);
#pragma unroll
    for (int nf = 0; nf < 4; nf++) {
      bf16x8 bfrag = *(const bf16x8*)(wp + (size_t)nf * 16 * EMBD + kc);
      acc[nf] = __builtin_amdgcn_mfma_f32_16x16x32_bf16(afrag, bfrag, acc[nf], 0, 0, 0);
    }
    if (hn) { xa = na; xb = nb; }
  }

  const int crow0 = rg * 64 + wave * 16 + lg * 4;
#pragma unroll
  for (int nf = 0; nf < 4; nf++) {
    const int nl = nf * 16 + l15;
    const float bs = bias[cs * 64 + nl];
#pragma unroll
    for (int i = 0; i < 4; i++) {
      const int r = crow0 + i;
      const unsigned short h = f2bf(acc[nf][i] + bs);
      if (cs == 0) {
        kws[(size_t)r * HEADD + nl] = h;
      } else if (cs == 1) {
        qws[(size_t)r * HEADD + nl] = h;
      } else {
        const int bb = r >> 12, sr = r & 4095;
        vtws[((size_t)bb * HEADD + nl) * S_LEN + sr] = h;  // V transposed
      }
    }
  }
}

// ---------------- Kernel 2: causal flash attention, kv-split 2 ----------------------
// grid 1024 (4 batch x 256 q-groups of 16 rows) x 128 threads (2 waves = 2 kv-splits)
// Swapped QK^T (mfma(K,Q) -> S^T): lane owns one q-row (q = lane&15); softmax is
// in-lane + 2 shfl_xor. No barriers in the kv loop (wave-private LDS bounce).
__global__ __launch_bounds__(128) void attn(
    const unsigned short* __restrict__ qws,
    const unsigned short* __restrict__ kws,
    const unsigned short* __restrict__ vtws,
    float* __restrict__ out) {
  __shared__ unsigned short pl[2][16][72];   // per-wave P bounce
  __shared__ float obuf[4][16][17];          // split-1 partial O
  __shared__ float mbuf[16];
  __shared__ float lbuf[16];

  const int w = threadIdx.x >> 6;            // kv-split index
  const int lane = threadIdx.x & 63;
  const int l15 = lane & 15, lg = lane >> 4;

  const int idx = blockIdx.x;
  const int b = idx & 3;
  const int idx2 = idx >> 2;                 // 0..255 q-group
  const int qt = (idx2 & 1) ? (idx2 >> 1) : (255 - (idx2 >> 1));  // heavy/light mix
  const int qbase = qt * 16;
  const int tlast = qbase >> 6;              // diagonal kv-tile

  const unsigned short* qp = qws + ((size_t)b * S_LEN + qbase + l15) * HEADD + lg * 8;
  const bf16x8 bq0 = *(const bf16x8*)qp;          // Q as B-operand (col = q)
  const bf16x8 bq1 = *(const bf16x8*)(qp + 32);

  const unsigned short* kb = kws + (size_t)b * S_LEN * HEADD;
  const unsigned short* vb = vtws + (size_t)b * HEADD * S_LEN;

  f32x4 o[4];
#pragma unroll
  for (int nd = 0; nd < 4; nd++) o[nd] = (f32x4){0.f, 0.f, 0.f, 0.f};
  float m = -3.0e38f, l = 0.f;

  if (w <= tlast) {
    bf16x8 ck0[4], ck1[4];
    {
      const unsigned short* kt = kb + ((size_t)w * 64 + l15) * HEADD + lg * 8;
#pragma unroll
      for (int nf = 0; nf < 4; nf++) {
        ck0[nf] = *(const bf16x8*)(kt + (size_t)nf * 16 * HEADD);
        ck1[nf] = *(const bf16x8*)(kt + (size_t)nf * 16 * HEADD + 32);
      }
    }
    for (int t = w; t <= tlast; t += 2) {
      // prefetch K(t+2) into registers (covers L2 latency across a full tile)
      bf16x8 nk0[4], nk1[4];
      const bool hn = (t + 2) <= tlast;
      if (hn) {
        const unsigned short* kt = kb + ((size_t)(t + 2) * 64 + l15) * HEADD + lg * 8;
#pragma unroll
        for (int nf = 0; nf < 4; nf++) {
          nk0[nf] = *(const bf16x8*)(kt + (size_t)nf * 16 * HEADD);
          nk1[nf] = *(const bf16x8*)(kt + (size_t)nf * 16 * HEADD + 32);
        }
      }
      // V(t): issued now, consumed after softmax (~240 cy of cover)
      bf16x8 v0[4], v1[4];
      {
        const unsigned short* vt = vb + (size_t)l15 * S_LEN + t * 64 + lg * 8;
#pragma unroll
        for (int nd = 0; nd < 4; nd++) {
          v0[nd] = *(const bf16x8*)(vt + (size_t)nd * 16 * S_LEN);
          v1[nd] = *(const bf16x8*)(vt + (size_t)nd * 16 * S_LEN + 32);
        }
      }
      // S^T tile: rows = kv, cols = q
      f32x4 sc[4];
#pragma unroll
      for (int nf = 0; nf < 4; nf++) {
        f32x4 z = (f32x4){0.f, 0.f, 0.f, 0.f};
        z = __builtin_amdgcn_mfma_f32_16x16x32_bf16(ck0[nf], bq0, z, 0, 0, 0);
        sc[nf] = __builtin_amdgcn_mfma_f32_16x16x32_bf16(ck1[nf], bq1, z, 0, 0, 0);
      }
      if (t == tlast) {
        const int qa = qbase + l15;
#pragma unroll
        for (int nf = 0; nf < 4; nf++)
#pragma unroll
          for (int i = 0; i < 4; i++)
            if (t * 64 + nf * 16 + lg * 4 + i > qa) sc[nf][i] = -1.0e30f;
      }
      // online softmax for q = l15 (lane-local + 2 shfls)
      float mx = sc[0][0];
#pragma unroll
      for (int nf = 0; nf < 4; nf++)
#pragma unroll
        for (int i = 0; i < 4; i++) mx = fmaxf(mx, sc[nf][i]);
      mx = fmaxf(mx, __shfl_xor(mx, 16));
      mx = fmaxf(mx, __shfl_xor(mx, 32));
      const float mn = fmaxf(m, mx);
      const float al = __builtin_amdgcn_exp2f(m - mn);
      m = mn;
      float rs = 0.f;
      float p[4][4];
#pragma unroll
      for (int nf = 0; nf < 4; nf++)
#pragma unroll
        for (int i = 0; i < 4; i++) {
          p[nf][i] = __builtin_amdgcn_exp2f(sc[nf][i] - m);
          rs += p[nf][i];
        }
      rs += __shfl_xor(rs, 16);
      rs += __shfl_xor(rs, 32);
      l = l * al + rs;
      // P -> LDS re-layout for PV A-frag (wave-private; no barrier needed)
#pragma unroll
      for (int nf = 0; nf < 4; nf++) {
        union { bf16x4 v; unsigned short s[4]; } u;
#pragma unroll
        for (int i = 0; i < 4; i++) u.s[i] = f2bf(p[nf][i]);
        *(bf16x4*)&pl[w][l15][nf * 16 + lg * 4] = u.v;
      }
      const bf16x8 ap0 = *(const bf16x8*)&pl[w][l15][lg * 8];
      const bf16x8 ap1 = *(const bf16x8*)&pl[w][l15][32 + lg * 8];
      // alpha redistributed from q=l15 lanes to O rows (q = lg*4+i)
      float alr[4];
#pragma unroll
      for (int i = 0; i < 4; i++) alr[i] = __shfl(al, lg * 4 + i);
#pragma unroll
      for (int nd = 0; nd < 4; nd++) {
        f32x4 oo = o[nd];
#pragma unroll
        for (int i = 0; i < 4; i++) oo[i] *= alr[i];
        oo = __builtin_amdgcn_mfma_f32_16x16x32_bf16(ap0, v0[nd], oo, 0, 0, 0);
        o[nd] = __builtin_amdgcn_mfma_f32_16x16x32_bf16(ap1, v1[nd], oo, 0, 0, 0);
      }
      if (hn) {
#pragma unroll
        for (int nf = 0; nf < 4; nf++) { ck0[nf] = nk0[nf]; ck1[nf] = nk1[nf]; }
      }
    }
  }

  // ---- merge the two kv-splits ----
  if (w == 1) {
    if (lane < 16) { mbuf[lane] = m; lbuf[lane] = l; }
#pragma unroll
    for (int nd = 0; nd < 4; nd++)
#pragma unroll
      for (int i = 0; i < 4; i++) obuf[nd][lg * 4 + i][l15] = o[nd][i];
  }
  __syncthreads();
  if (w == 0) {
    const float m1 = mbuf[l15], l1 = lbuf[l15];
    const float M = fmaxf(m, m1);
    const float a0 = __builtin_amdgcn_exp2f(m - M);
    const float a1 = __builtin_amdgcn_exp2f(m1 - M);
    const float iL = 1.0f / (l * a0 + l1 * a1);
    const float f0 = a0 * iL, f1 = a1 * iL;
    float f0r[4], f1r[4];
#pragma unroll
    for (int i = 0; i < 4; i++) {
      f0r[i] = __shfl(f0, lg * 4 + i);
      f1r[i] = __shfl(f1, lg * 4 + i);
    }
#pragma unroll
    for (int nd = 0; nd < 4; nd++)
#pragma unroll
      for (int i = 0; i < 4; i++) {
        const float val = o[nd][i] * f0r[i] + obuf[nd][lg * 4 + i][l15] * f1r[i];
        out[((size_t)b * S_LEN + qbase + lg * 4 + i) * HEADD + nd * 16 + l15] = val;
      }
  }
}

extern "C" void kernel_launch(void* const* d_in, const int* in_sizes, int n_in,
                              void* d_out, int out_size, void* d_ws, size_t ws_size,
                              hipStream_t stream) {
  const float* X  = (const float*)d_in[0];
  const float* Wk = (const float*)d_in[1];
  const float* bk = (const float*)d_in[2];
  const float* Wq = (const float*)d_in[3];
  const float* bq = (const float*)d_in[4];
  const float* Wv = (const float*)d_in[5];
  const float* bv = (const float*)d_in[6];
  float* out = (float*)d_out;

  char* ws = (char*)d_ws;
  unsigned short* kws  = (unsigned short*)(ws);                      // 2 MB
  unsigned short* qws  = (unsigned short*)(ws + (2u << 20));         // 2 MB
  unsigned short* vtws = (unsigned short*)(ws + (4u << 20));         // 2 MB (transposed)
  unsigned short* wt   = (unsigned short*)(ws + (6u << 20));         // 384 KB
  float*          bias = (float*)(ws + (6u << 20) + (512u << 10));   // 768 B

  prep_w<<<dim3(192), dim3(256), 0, stream>>>(Wk, bk, Wq, bq, Wv, bv, wt, bias);
  proj_qkv<<<dim3(768), dim3(256), 0, stream>>>(X, wt, bias, qws, kws, vtws);
  attn<<<dim3(1024), dim3(128), 0, stream>>>(qws, kws, vtws, out);
}